// Round 1
// 368.353 us; speedup vs baseline: 1.1366x; 1.1366x over previous
//
#include <hip/hip_runtime.h>
#include <stdint.h>
#include <math.h>

// Problem constants
#define NTOK 8192   // B*S tokens
#define FIN  4096
#define FOUT 4096
#define PP   512
#define QIN  8
#define QOUT 8
#define NFREQ 257   // P/2+1

// ---------------------------------------------------------------------------
// complex helpers
// ---------------------------------------------------------------------------
__device__ __forceinline__ float2 cadd(float2 a, float2 b) { return make_float2(a.x + b.x, a.y + b.y); }
__device__ __forceinline__ float2 csub(float2 a, float2 b) { return make_float2(a.x - b.x, a.y - b.y); }

// a * t, conjugating t when INV (t from forward twiddle tables, W = e^{-2pi i/512})
template<int INV>
__device__ __forceinline__ float2 twmul(float2 a, float2 t) {
    const float ty = INV ? -t.y : t.y;
    return make_float2(a.x * t.x - a.y * ty, a.x * ty + a.y * t.x);
}

// ---------------------------------------------------------------------------
// In-register 8-point DFT over the register index:
//   Z[k] = sum_j z[j] * w8^{jk},  w8 = e^{-2pi i/8} (conj when INV).
// Verified against delta inputs (z=delta_1 -> Z_k = w8^{+-k}).
// ---------------------------------------------------------------------------
template<int INV>
__device__ __forceinline__ void dft8(float2 z[8]) {
    const float S = 0.70710678118654752f;
    float2 a0 = cadd(z[0], z[4]), a4 = csub(z[0], z[4]);
    float2 a1 = cadd(z[1], z[5]), a5 = csub(z[1], z[5]);
    float2 a2 = cadd(z[2], z[6]), a6 = csub(z[2], z[6]);
    float2 a3 = cadd(z[3], z[7]), a7 = csub(z[3], z[7]);
    // even outputs: DFT4(a0..a3)
    float2 b0 = cadd(a0, a2), b2 = csub(a0, a2);
    float2 b1 = cadd(a1, a3), b3 = csub(a1, a3);
    z[0] = cadd(b0, b1);
    z[4] = csub(b0, b1);
    float2 r3 = INV ? make_float2(-b3.y, b3.x) : make_float2(b3.y, -b3.x);   // -+i * b3
    z[2] = cadd(b2, r3);
    z[6] = csub(b2, r3);
    // odd outputs: c_j = a_{4+j} * w8^j, then DFT4
    float2 c0 = a4;
    float2 c1 = INV ? make_float2(S * (a5.x - a5.y), S * (a5.x + a5.y))
                    : make_float2(S * (a5.x + a5.y), S * (a5.y - a5.x));
    float2 c2 = INV ? make_float2(-a6.y, a6.x) : make_float2(a6.y, -a6.x);
    float2 c3 = INV ? make_float2(-S * (a7.x + a7.y), S * (a7.x - a7.y))
                    : make_float2(S * (a7.y - a7.x), -S * (a7.x + a7.y));
    float2 d0 = cadd(c0, c2), d2 = csub(c0, c2);
    float2 d1 = cadd(c1, c3), d3 = csub(c1, c3);
    z[1] = cadd(d0, d1);
    z[5] = csub(d0, d1);
    float2 r7 = INV ? make_float2(-d3.y, d3.x) : make_float2(d3.y, -d3.x);
    z[3] = cadd(d2, r7);
    z[7] = csub(d2, r7);
}

// ---------------------------------------------------------------------------
// Per-wave 512-point FFT, four-step radix-8^3.
//   n = 64*n2 + 8*n1 + n0 ; k = k0 + 8*k1 + 64*k2
// Input : reg r of lane L = x[64*r + L]          (natural)
// Output: reg r of lane L = X[64*r + L]          (natural!)
// Stages: DFT8(n2->k0) ; *W64^{n1*k0} ; T1 ; DFT8(n1->k1) ; *W^{n0(k0+8k1)} ;
//         T2 ; DFT8(n0->k2).  Transposes through Mt (rows padded to 68 float2,
//         all patterns 4 lanes/bank-pair = conflict-free).  Same-wave DS ops
//         are in-order -> no barriers.
// ---------------------------------------------------------------------------
template<int INV>
__device__ __forceinline__ void fft512(float2 z[8], float2* Mt, const float2* tw,
                                       const float2* twA, const int lane,
                                       const int h, const int w) {
    dft8<INV>(z);                              // over n2 -> k0
#pragma unroll
    for (int k = 1; k < 8; ++k)                // TA: * W64^{h*k} (h = n1 here)
        z[k] = twmul<INV>(z[k], twA[h * 9 + k]);
#pragma unroll
    for (int k = 0; k < 8; ++k) Mt[k * 68 + lane] = z[k];          // T1 write
#pragma unroll
    for (int k = 0; k < 8; ++k) z[k] = Mt[h * 68 + 8 * k + w];     // T1 read
    dft8<INV>(z);                              // over n1 -> k1   (now h=k0, w=n0)
#pragma unroll
    for (int k = 0; k < 8; ++k)                // TB: * W512^{w*(h+8k)}
        z[k] = twmul<INV>(z[k], tw[(w * (h + 8 * k)) & 511]);
#pragma unroll
    for (int k = 0; k < 8; ++k) Mt[k * 68 + 8 * w + h] = z[k];     // T2 write
#pragma unroll
    for (int k = 0; k < 8; ++k) z[k] = Mt[h * 68 + 8 * k + w];     // T2 read
    dft8<INV>(z);                              // over n0 -> k2
}

// ---------------------------------------------------------------------------
// wf_build: WfT[(o*8+i)*257 + f] = (1/512) * DFT_512(w[o][i])[f]
// Transposed [oi][f] layout -> einsum weight loads are lane-coalesced.
// 4-way split of the n-sum across waves + LDS reduce (kills the 512-long
// serial loop; per-block time ~ 5*128 iters).
// ---------------------------------------------------------------------------
__global__ __launch_bounds__(256) void wf_build(const float* __restrict__ w,
                                                float2* __restrict__ WfT) {
    __shared__ float  sw[512];
    __shared__ float2 tb[512];          // tb[k] = W^k = (cos, -sin)(2pi k/512)
    __shared__ float2 red[4][64];
    const int blk = blockIdx.x;         // o*8 + i
    const float* wrow = w + (size_t)blk * 512;
    const int t   = threadIdx.x;
    const int fi  = t & 63;
    const int seg = t >> 6;
    sw[t]       = wrow[t];
    sw[t + 256] = wrow[t + 256];
    const float th = -6.283185307179586f / 512.0f;
    {
        float a0 = th * (float)t, a1 = th * (float)(t + 256);
        tb[t]       = make_float2(cosf(a0), sinf(a0));
        tb[t + 256] = make_float2(cosf(a1), sinf(a1));
    }
    __syncthreads();
    for (int g = 0; g < 5; ++g) {
        const int f = (g < 4) ? (g * 64 + fi) : 256;
        float re = 0.f, im = 0.f;
        int idx = (f * (seg * 128)) & 511;
        for (int n = 0; n < 128; ++n) {
            const float2 e = tb[idx];
            const float  v = sw[seg * 128 + n];
            re += v * e.x;
            im += v * e.y;
            idx = (idx + f) & 511;
        }
        red[seg][fi] = make_float2(re, im);
        __syncthreads();
        if (seg == 0) {
            float2 r0 = red[0][fi], r1 = red[1][fi], r2 = red[2][fi], r3 = red[3][fi];
            float rre = (r0.x + r1.x) + (r2.x + r3.x);
            float rim = (r0.y + r1.y) + (r2.y + r3.y);
            if (g < 4 || fi == 0)
                WfT[(size_t)blk * 257 + f] = make_float2(rre * (1.f / 512.f),
                                                         rim * (1.f / 512.f));
        }
        __syncthreads();
    }
}

// ---------------------------------------------------------------------------
// fft_conv: one block (256 thr, 4 waves) per token.  Wave c handles packed
// complex sequence Z_c = xs[2c] + i*xs[2c+1].
//   pack (regs, coalesced) -> fft512 fwd (regs + 2 LDS transposes)
//   -> spectra to LDS (natural order) -> barrier -> einsum (coalesced WfT)
//   -> barrier -> fft512 inv -> bias+GELU epilogue (regs, coalesced stores)
// LDS (float2 units):
//   ZS  [0,2048)      : c*512 + idx   fwd spectra
//   VS  [2048,4224)   : 2048 + c*544  einsum output spectra; per-wave Mt scratch
//   tw  [4224,4736)   : W512^k table
//   twA [4736,4808)   : h*9+k -> W512^{8hk} (padded to kill bank conflicts)
// ---------------------------------------------------------------------------
__global__ __launch_bounds__(256) void fft_conv(const float* __restrict__ x,
                                                const int* __restrict__ sign_bits,
                                                const float2* __restrict__ WfT,
                                                const float* __restrict__ bias,
                                                float* __restrict__ out) {
    __shared__ float2 LB[4808];

    const int tid  = threadIdx.x;
    const int wave = tid >> 6;
    const int lane = tid & 63;
    const int h = lane >> 3, w = lane & 7;
    const float* xin  = x   + (size_t)blockIdx.x * FIN;
    float*       yout = out + (size_t)blockIdx.x * FOUT;

    // ---- twiddle tables ----
    {
        const float th = -6.283185307179586f / 512.0f;
        float a0 = th * (float)tid, a1 = th * (float)(tid + 256);
        LB[4224 + tid]       = make_float2(cosf(a0), sinf(a0));
        LB[4224 + tid + 256] = make_float2(cosf(a1), sinf(a1));
        if (tid < 64) {
            int hh = tid >> 3, kk = tid & 7;
            float ang = th * (float)(8 * hh * kk);
            LB[4736 + hh * 9 + kk] = make_float2(cosf(ang), sinf(ang));
        }
    }
    __syncthreads();

    const float2* tw  = &LB[4224];
    const float2* twA = &LB[4736];
    float2* Mt  = &LB[2048 + wave * 544];
    float2* ZSc = &LB[wave * 512];

    // ---- pack x*sign into registers (reg k = element 64k+lane) ----
    float2 z[8];
    {
        const float* xre = xin + (2 * wave) * 512;
        const float* xim = xin + (2 * wave + 1) * 512;
        const int*   sre = sign_bits + (2 * wave) * 512;
        const int*   sim = sign_bits + (2 * wave + 1) * 512;
#pragma unroll
        for (int k = 0; k < 8; ++k) {
            const int p = 64 * k + lane;
            float a = xre[p], b = xim[p];
            unsigned sa = (unsigned)sre[p] << 31;
            unsigned sb = (unsigned)sim[p] << 31;
            z[k].x = __uint_as_float(__float_as_uint(a) ^ sa);
            z[k].y = __uint_as_float(__float_as_uint(b) ^ sb);
        }
    }

    // ---- forward FFT (wave-private) ----
    fft512<0>(z, Mt, tw, twA, lane, h, w);

#pragma unroll
    for (int k = 0; k < 8; ++k) ZSc[64 * k + lane] = z[k];
    __syncthreads();

    // ---- spectral einsum (Hermitian unpack -> 8x8 complex MAC -> repack) ----
    for (int f = tid; f <= 256; f += 256) {     // thread 0 also does f=256
        const int fm = (512 - f) & 511;
        float2 Xf[8];
#pragma unroll
        for (int c = 0; c < 4; ++c) {
            const float2 zp = LB[c * 512 + f];
            const float2 zm = LB[c * 512 + fm];
            Xf[2 * c]     = make_float2(0.5f * (zp.x + zm.x), 0.5f * (zp.y - zm.y));
            Xf[2 * c + 1] = make_float2(0.5f * (zp.y + zm.y), -0.5f * (zp.x - zm.x));
        }
        float2 Y[8];
#pragma unroll
        for (int o = 0; o < 8; ++o) {
            float re = 0.f, im = 0.f;
#pragma unroll
            for (int i = 0; i < 8; ++i) {
                const float2 xv = Xf[i];
                const float2 wv = WfT[(o * 8 + i) * 257 + f];   // coalesced
                re += xv.x * wv.x - xv.y * wv.y;
                im += xv.x * wv.y + xv.y * wv.x;
            }
            Y[o] = make_float2(re, im);
        }
#pragma unroll
        for (int c = 0; c < 4; ++c) {
            const float2 y0 = Y[2 * c], y1 = Y[2 * c + 1];
            LB[2048 + c * 544 + f] = make_float2(y0.x - y1.y, y0.y + y1.x);
            if (f != 0 && f != 256)
                LB[2048 + c * 544 + 512 - f] = make_float2(y0.x + y1.y, y1.x - y0.y);
        }
    }
    __syncthreads();

    // ---- inverse FFT (1/512 folded into WfT) ----
#pragma unroll
    for (int k = 0; k < 8; ++k) z[k] = LB[2048 + wave * 544 + 64 * k + lane];

    fft512<1>(z, Mt, tw, twA, lane, h, w);

    // ---- epilogue: bias + exact GELU, coalesced dword stores ----
    {
        const float* bre = bias + (2 * wave) * 512;
        const float* bim = bias + (2 * wave + 1) * 512;
        float* yre = yout + (2 * wave) * 512;
        float* yim = yout + (2 * wave + 1) * 512;
#pragma unroll
        for (int k = 0; k < 8; ++k) {
            const int p = 64 * k + lane;
            float v0 = z[k].x + bre[p];
            float v1 = z[k].y + bim[p];
            yre[p] = 0.5f * v0 * (1.0f + erff(v0 * 0.70710678118654752f));
            yim[p] = 0.5f * v1 * (1.0f + erff(v1 * 0.70710678118654752f));
        }
    }
}

extern "C" void kernel_launch(void* const* d_in, const int* in_sizes, int n_in,
                              void* d_out, int out_size, void* d_ws, size_t ws_size,
                              hipStream_t stream) {
    const float* x        = (const float*)d_in[0];   // [B,S,F_IN] fp32
    const float* w        = (const float*)d_in[1];   // [QOUT,QIN,P] fp32
    const float* bias     = (const float*)d_in[2];   // [F_OUT] fp32
    const int*  sign_bits = (const int*)d_in[3];     // [F_IN] int32
    float* out = (float*)d_out;                      // [B,S,F_OUT] fp32

    float2* WfT = (float2*)d_ws;                     // [64][257] complex = 131.6 KB

    wf_build<<<QOUT * QIN, 256, 0, stream>>>(w, WfT);
    fft_conv<<<NTOK, 256, 0, stream>>>(x, sign_bits, WfT, bias, out);
}